// Round 3
// baseline (81.301 us; speedup 1.0000x reference)
//
#include <hip/hip_runtime.h>

#define NQ 10
#define NL 3

typedef float v2f __attribute__((ext_vector_type(2)));
typedef unsigned int u2 __attribute__((ext_vector_type(2)));

__device__ __forceinline__ int   f2i(float v) { union { float f; int i; } u; u.f = v; return u.i; }
__device__ __forceinline__ float i2f(int v)   { union { int i; float f; } u; u.i = v; return u.f; }

// ---- packed-f32 complex helpers (gfx950 full-rate VOP3P) -------------------
// cmul: (a.x+ia.y)*(b.x+ib.y). Same fma ordering as scalar version:
//   re = ax*bx fma(-ay,by)   im = ax*by fma(ay,bx)
__device__ __forceinline__ v2f cmul(v2f a, v2f b) {
    v2f d;
    asm("v_pk_mul_f32 %0, %1, %2 op_sel:[0,0] op_sel_hi:[0,1]"
        : "=v"(d) : "v"(a), "v"(b));                       // (ax*bx, ax*by)
    asm("v_pk_fma_f32 %0, %1, %2, %0 op_sel:[1,1,0] op_sel_hi:[1,0,1] neg_lo:[0,1,0]"
        : "+v"(d) : "v"(a), "v"(b));                       // (+= -ay*by, += ay*bx)
    return d;
}

// A*cs.x + B*cs.y elementwise (2 instr, replaces 4 scalar FMAs)
__device__ __forceinline__ v2f pk_ab(v2f A, v2f B, v2f cs) {
    v2f d;
    asm("v_pk_mul_f32 %0, %1, %2 op_sel:[0,1] op_sel_hi:[1,1]"
        : "=v"(d) : "v"(B), "v"(cs));                      // (B.x*s, B.y*s)
    asm("v_pk_fma_f32 %0, %1, %2, %0 op_sel:[0,0,0] op_sel_hi:[1,0,1]"
        : "+v"(d) : "v"(A), "v"(cs));                      // += (A.x*c, A.y*c)
    return d;
}
// A*cs.x - B*cs.y elementwise
__device__ __forceinline__ v2f pk_ab_n(v2f A, v2f B, v2f cs) {
    v2f d;
    asm("v_pk_mul_f32 %0, %1, %2 op_sel:[0,1] op_sel_hi:[1,1] neg_lo:[1,0] neg_hi:[1,0]"
        : "=v"(d) : "v"(B), "v"(cs));                      // (-B.x*s, -B.y*s)
    asm("v_pk_fma_f32 %0, %1, %2, %0 op_sel:[0,0,0] op_sel_hi:[1,0,1]"
        : "+v"(d) : "v"(A), "v"(cs));
    return d;
}

template<int C> __device__ __forceinline__ int dppm(int v) {
    return __builtin_amdgcn_mov_dpp(v, C, 0xF, 0xF, false);
}

// ---- xor-exchange within a 16-lane row, composed from the verified DPP set:
// xor1=quad[1032]=177, xor2=quad[2301]=78, xor3=quad[3210]=27,
// xor7=row_half_mirror=321, xor15=row_mirror=320. All zero-latency VALU. ----
template<int M> __device__ __forceinline__ int dpp_xor(int v) {
    if constexpr (M == 0)       return v;
    else if constexpr (M == 1)  return dppm<177>(v);
    else if constexpr (M == 2)  return dppm<78>(v);
    else if constexpr (M == 3)  return dppm<27>(v);
    else if constexpr (M == 4)  return dppm<321>(dppm<27>(v));    // 3^7
    else if constexpr (M == 5)  return dppm<321>(dppm<78>(v));    // 2^7
    else if constexpr (M == 6)  return dppm<321>(dppm<177>(v));   // 1^7
    else if constexpr (M == 7)  return dppm<321>(v);
    else if constexpr (M == 8)  return dppm<320>(dppm<321>(v));   // 7^15
    else if constexpr (M == 9)  return dppm<320>(dppm<321>(dppm<177>(v)));
    else if constexpr (M == 10) return dppm<320>(dppm<321>(dppm<78>(v)));
    else if constexpr (M == 11) return dppm<320>(dppm<321>(dppm<27>(v)));
    else if constexpr (M == 12) return dppm<320>(dppm<27>(v));    // 3^15
    else if constexpr (M == 13) return dppm<320>(dppm<78>(v));    // 2^15
    else if constexpr (M == 14) return dppm<320>(dppm<177>(v));   // 1^15
    else                        return dppm<320>(v);              // 15
}

// ---- gfx950 permlane swap BUILTINS (compiler-visible: scheduler + hazard
// nops handled, unlike the R2 raw-asm attempt which hit the VALU->permlane
// read hazard). Builtin returns {new_vdst, new_vsrc}. Double-swap realizes a
// full xorN exchange of BOTH registers, convention-independent:
//   r1 = swap(X,Y); r2 = swap(r1[1], r1[0]) -> r2[0]=xorN(X), r2[1]=xorN(Y)
__device__ __forceinline__ void pl16_pair(int &x, int &y) {
    u2 r1 = __builtin_amdgcn_permlane16_swap((unsigned)x, (unsigned)y, false, false);
    u2 r2 = __builtin_amdgcn_permlane16_swap(r1[1], r1[0], false, false);
    x = (int)r2[0]; y = (int)r2[1];
}
__device__ __forceinline__ void pl32_pair(int &x, int &y) {
    u2 r1 = __builtin_amdgcn_permlane32_swap((unsigned)x, (unsigned)y, false, false);
    u2 r2 = __builtin_amdgcn_permlane32_swap(r1[1], r1[0], false, false);
    x = (int)r2[0]; y = (int)r2[1];
}

// ---- lane exchange by xor mask LM — pure VALU (R1 theory: DS pipe + lgkmcnt
// serialization was the bottleneck; all exchanges now DPP + permlane swap) --
template<int LM>
__device__ __forceinline__ v2f xlane(v2f v) {
    if constexpr (LM == 0) return v;
    int x = f2i(v.x), y = f2i(v.y);
    constexpr int L = LM & 15;
    x = dpp_xor<L>(x);
    y = dpp_xor<L>(y);
    if constexpr (LM & 16) pl16_pair(x, y);
    if constexpr (LM & 32) pl32_pair(x, y);
    return (v2f){ i2f(x), i2f(y) };
}

// scalar xor16 / xor32 for the measurement reduce (double-swap on a copy;
// r2[0] = xorN(F) under either row-swap convention)
__device__ __forceinline__ float x16s(float f) {
    unsigned p = (unsigned)f2i(f);
    u2 r1 = __builtin_amdgcn_permlane16_swap(p, p, false, false);
    u2 r2 = __builtin_amdgcn_permlane16_swap(r1[1], r1[0], false, false);
    return i2f((int)r2[0]);
}
__device__ __forceinline__ float x32s(float f) {
    unsigned p = (unsigned)f2i(f);
    u2 r1 = __builtin_amdgcn_permlane32_swap(p, p, false, false);
    u2 r2 = __builtin_amdgcn_permlane32_swap(r1[1], r1[0], false, false);
    return i2f((int)r2[0]);
}

// Generalized single-qubit gate under GF(2) index transform (masks verified
// R2-R11). Packed-f32 math: 4 VOP3P per amp, identical IEEE rounding order.
// Slot parity SP is compile-time so coefficient choice is free.
template<int MASK, int RMASK>
__device__ __forceinline__ void apply_gate(v2f (&a)[16], float4 r0, float4 r1,
                                           float cq, float sq, int lane)
{
    constexpr int LM = (MASK >> 4) & 63;
    constexpr int JM = MASK & 15;
    constexpr int RH = (RMASK >> 4) & 63;
    constexpr int RL = RMASK & 15;

    // fuse Rot * RY(c,s): 8 packed instr
    const v2f vcs = { cq, sq };
    const v2f r0a = { r0.x, r0.y }, r0b = { r0.z, r0.w };
    const v2f r1a = { r1.x, r1.y }, r1b = { r1.z, r1.w };
    const v2f g00 = pk_ab  (r0a, r0b, vcs);   // (g00r, g00i)
    const v2f g01 = pk_ab_n(r0b, r0a, vcs);   // (g01r, g01i)
    const v2f g10 = pk_ab  (r1a, r1b, vcs);
    const v2f g11 = pk_ab_n(r1b, r1a, vcs);

    const bool lp = (RH != 0) && (__popc(lane & RH) & 1);
    // parity-0 (total parity even) and parity-1 coefficient sets, (re,im) pairs
    const v2f A0 = lp ? g11 : g00;
    const v2f B0 = lp ? g10 : g01;
    const v2f A1 = lp ? g00 : g11;
    const v2f B1 = lp ? g01 : g10;

    // phase 1: all partner values (independent -> deep DPP/permlane ILP)
    v2f o[16];
    #pragma unroll
    for (int j = 0; j < 16; ++j) o[j] = xlane<LM>(a[j ^ JM]);

    // phase 2: new = A (x) a + B (x) o (complex), 4 packed FMA-class instr/amp
#define QNN_F(J) { constexpr int SP_ = __builtin_popcount((J) & RL) & 1;      \
    const v2f CA = SP_ ? A1 : A0;                                             \
    const v2f CB = SP_ ? B1 : B0;                                             \
    const v2f av = a[J]; const v2f ov = o[J];                                 \
    v2f d;                                                                    \
    asm("v_pk_mul_f32 %0, %1, %2 op_sel:[0,0] op_sel_hi:[0,1]"                \
        : "=v"(d) : "v"(CA), "v"(av));          /* (Ar*ar, Ar*ai) */          \
    asm("v_pk_fma_f32 %0, %1, %2, %0 op_sel:[1,1,0] op_sel_hi:[1,0,1] neg_lo:[0,1,0]" \
        : "+v"(d) : "v"(CA), "v"(av));          /* (-Ai*ai, +Ai*ar) */        \
    asm("v_pk_fma_f32 %0, %1, %2, %0 op_sel:[0,0,0] op_sel_hi:[0,1,1]"        \
        : "+v"(d) : "v"(CB), "v"(ov));          /* (+Br*pr, +Br*pi) */        \
    asm("v_pk_fma_f32 %0, %1, %2, %0 op_sel:[1,1,0] op_sel_hi:[1,0,1] neg_lo:[0,1,0]" \
        : "+v"(d) : "v"(CB), "v"(ov));          /* (-Bi*pi, +Bi*pr) */        \
    a[J] = d; }
    QNN_F(0) QNN_F(1) QNN_F(2) QNN_F(3) QNN_F(4) QNN_F(5) QNN_F(6) QNN_F(7)
    QNN_F(8) QNN_F(9) QNN_F(10) QNN_F(11) QNN_F(12) QNN_F(13) QNN_F(14) QNN_F(15)
#undef QNN_F
}

__global__ __launch_bounds__(256, 4)
void qnn_kernel(const float* __restrict__ x, const float* __restrict__ w,
                float* __restrict__ out)
{
    __shared__ float4 rotL[NL * NQ][2];   // (R00,R01) | (R10,R11)

    const int t    = threadIdx.x;
    const int lane = t & 63;
    const int b    = blockIdx.x * 4 + (t >> 6);   // one wave per batch element

    if (t < NL * NQ) {
        const float* wp = w + t * 3;
        float phi = wp[0], th = wp[1], om = wp[2];
        float ct = cosf(th * 0.5f), st = sinf(th * 0.5f);
        float ap = (phi + om) * 0.5f, am = (phi - om) * 0.5f;
        float cap = cosf(ap), sap = sinf(ap);
        float cam = cosf(am), sam = sinf(am);
        rotL[t][0] = make_float4(cap * ct, -sap * ct, -cam * st, -sam * st);
        rotL[t][1] = make_float4(cam * st, -sam * st,  cap * ct,  sap * ct);
    }
    __syncthreads();

    // ---- per-batch RY cos/sin (wave-uniform -> SGPR via readfirstlane) ----
    const float* xb = x + (size_t)__builtin_amdgcn_readfirstlane(b * NQ);
    float c_[NQ], s_[NQ];
    #pragma unroll
    for (int q = 0; q < NQ; ++q) {
        float xv = xb[q] * 0.5f;
        c_[q] = i2f(__builtin_amdgcn_readfirstlane(f2i(__cosf(xv))));
        s_[q] = i2f(__builtin_amdgcn_readfirstlane(f2i(__sinf(xv))));
    }

    // ---- layer 1 analytic: product state amp[p] = prod_q col0(G_q)[bit_q(p)] ----
    v2f c0[4], c1[4];
    v2f Ln = {1.f, 0.f};
    #pragma unroll
    for (int q = 0; q < NQ; ++q) {
        float4 r0 = rotL[q][0], r1 = rotL[q][1];
        const v2f vcs = { c_[q], s_[q] };
        const v2f r0a = { r0.x, r0.y }, r0b = { r0.z, r0.w };
        const v2f r1a = { r1.x, r1.y }, r1b = { r1.z, r1.w };
        v2f g0 = pk_ab(r0a, r0b, vcs);
        v2f g1 = pk_ab(r1a, r1b, vcs);
        if (q < 4) { c0[q] = g0; c1[q] = g1; }
        else {
            v2f gg = ((lane >> (q - 4)) & 1) ? g1 : g0;
            Ln = (q == 4) ? gg : cmul(Ln, gg);
        }
    }
    v2f S01[4], SH[4];
    #pragma unroll
    for (int j = 0; j < 4; ++j)
        S01[j] = cmul((j & 1) ? c1[0] : c0[0], (j & 2) ? c1[1] : c0[1]);
    #pragma unroll
    for (int h = 0; h < 4; ++h)
        SH[h] = cmul(cmul((h & 1) ? c1[2] : c0[2], (h & 2) ? c1[3] : c0[3]), Ln);
    v2f a[16];
    #pragma unroll
    for (int j = 0; j < 16; ++j)
        a[j] = cmul(S01[j & 3], SH[j >> 2]);

    // ---- layers 2..3 (masks + parities verified in R2/R3/R5/R8) ----
#define GATE(IDX, Q, MASK, RMASK) \
    apply_gate<MASK, RMASK>(a, rotL[IDX][0], rotL[IDX][1], c_[Q], s_[Q], lane);
    GATE(10, 0, 0x003, 0x3FE)  GATE(11, 1, 0x006, 0x003)
    GATE(12, 2, 0x00C, 0x007)  GATE(13, 3, 0x018, 0x00F)
    GATE(14, 4, 0x030, 0x01F)  GATE(15, 5, 0x060, 0x03F)
    GATE(16, 6, 0x0C0, 0x07F)  GATE(17, 7, 0x180, 0x0FF)
    GATE(18, 8, 0x300, 0x1FF)  GATE(19, 9, 0x203, 0x3FF)
    GATE(20, 0, 0x005, 0x2AB)  GATE(21, 1, 0x00A, 0x3FD)
    GATE(22, 2, 0x014, 0x3FA)  GATE(23, 3, 0x028, 0x3F5)
    GATE(24, 4, 0x050, 0x3EA)  GATE(25, 5, 0x0A0, 0x3D5)
    GATE(26, 6, 0x140, 0x3AA)  GATE(27, 7, 0x280, 0x355)
    GATE(28, 8, 0x103, 0x2AA)  GATE(29, 9, 0x206, 0x155)
#undef GATE

    // ---- probabilities + 4-bit Walsh-Hadamard over slots ----
    float P[16];
    #pragma unroll
    for (int j = 0; j < 16; ++j)
        P[j] = fmaf(a[j].x, a[j].x, a[j].y * a[j].y);
    #pragma unroll
    for (int bit = 0; bit < 4; ++bit) {
        #pragma unroll
        for (int j = 0; j < 16; ++j)
            if (!(j & (1 << bit))) {
                int k = j | (1 << bit);
                float u = P[j], v = P[k];
                P[j] = u + v;
                P[k] = u - v;
            }
    }

    float vout = 0.f;
#define MEAS(Q, RM)                                                           \
    { constexpr int RH_ = ((RM) >> 4) & 63;                                   \
      constexpr int RL_ = (RM) & 15;                                          \
      float v = P[RL_];                                                       \
      if (__popc(lane & RH_) & 1) v = -v;                                     \
      v += i2f(dppm<177>(f2i(v)));                 /* xor1  */                \
      v += i2f(dppm<78>(f2i(v)));                  /* xor2  */                \
      v += i2f(dppm<321>(dppm<27>(f2i(v))));       /* xor4 = 7^3 */           \
      v += i2f(dppm<320>(dppm<321>(f2i(v))));      /* xor8 = 15^7 */          \
      v += x16s(v);                                /* xor16 */                \
      v += x32s(v);                                /* xor32 */                \
      if (lane == (Q)) vout = v; }
    MEAS(0, 0x0CD) MEAS(1, 0x156) MEAS(2, 0x2AC) MEAS(3, 0x159)
    MEAS(4, 0x2B3) MEAS(5, 0x166) MEAS(6, 0x2CC) MEAS(7, 0x199)
    MEAS(8, 0x333) MEAS(9, 0x266)
#undef MEAS

    if (lane < NQ) out[b * NQ + lane] = vout;
}

extern "C" void kernel_launch(void* const* d_in, const int* in_sizes, int n_in,
                              void* d_out, int out_size, void* d_ws, size_t ws_size,
                              hipStream_t stream) {
    const float* x = (const float*)d_in[0];   // (4096, 10) f32
    const float* w = (const float*)d_in[1];   // (3, 10, 3) f32
    float* out = (float*)d_out;               // (4096, 10) f32
    const int B = in_sizes[0] / NQ;           // 4096
    qnn_kernel<<<B / 4, 256, 0, stream>>>(x, w, out);
}

// Round 4
// 77.349 us; speedup vs baseline: 1.0511x; 1.0511x over previous
//
#include <hip/hip_runtime.h>

#define NQ 10
#define NL 3

typedef float v2f __attribute__((ext_vector_type(2)));
typedef unsigned int u2 __attribute__((ext_vector_type(2)));

__device__ __forceinline__ int   f2i(float v) { union { float f; int i; } u; u.f = v; return u.i; }
__device__ __forceinline__ float i2f(int v)   { union { int i; float f; } u; u.i = v; return u.f; }

// ---- packed-f32 complex helpers (VOP3P; note: packed f32 is issue-slot
// savings only on gfx950 — same 32 FMA units — so VALU work must be MOVED
// off-pipe (DS), not "packed harder". R3 lesson.) ----------------------------
__device__ __forceinline__ v2f cmul(v2f a, v2f b) {
    v2f d;
    asm("v_pk_mul_f32 %0, %1, %2 op_sel:[0,0] op_sel_hi:[0,1]"
        : "=v"(d) : "v"(a), "v"(b));                       // (ax*bx, ax*by)
    asm("v_pk_fma_f32 %0, %1, %2, %0 op_sel:[1,1,0] op_sel_hi:[1,0,1] neg_lo:[0,1,0]"
        : "+v"(d) : "v"(a), "v"(b));                       // (+= -ay*by, += ay*bx)
    return d;
}

// A*cs.x + B*cs.y elementwise
__device__ __forceinline__ v2f pk_ab(v2f A, v2f B, v2f cs) {
    v2f d;
    asm("v_pk_mul_f32 %0, %1, %2 op_sel:[0,1] op_sel_hi:[1,1]"
        : "=v"(d) : "v"(B), "v"(cs));                      // (B.x*s, B.y*s)
    asm("v_pk_fma_f32 %0, %1, %2, %0 op_sel:[0,0,0] op_sel_hi:[1,0,1]"
        : "+v"(d) : "v"(A), "v"(cs));                      // += (A.x*c, A.y*c)
    return d;
}
// A*cs.x - B*cs.y elementwise
__device__ __forceinline__ v2f pk_ab_n(v2f A, v2f B, v2f cs) {
    v2f d;
    asm("v_pk_mul_f32 %0, %1, %2 op_sel:[0,1] op_sel_hi:[1,1] neg_lo:[1,0] neg_hi:[1,0]"
        : "=v"(d) : "v"(B), "v"(cs));                      // (-B.x*s, -B.y*s)
    asm("v_pk_fma_f32 %0, %1, %2, %0 op_sel:[0,0,0] op_sel_hi:[1,0,1]"
        : "+v"(d) : "v"(A), "v"(cs));
    return d;
}

template<int C> __device__ __forceinline__ int dppm(int v) {
    return __builtin_amdgcn_mov_dpp(v, C, 0xF, 0xF, false);
}

// ---- gfx950 permlane swap builtins (R3-proven correct; hazards handled by
// compiler). Double-swap = xorN exchange of BOTH regs, convention-free. ----
__device__ __forceinline__ void pl16_pair(int &x, int &y) {
    u2 r1 = __builtin_amdgcn_permlane16_swap((unsigned)x, (unsigned)y, false, false);
    u2 r2 = __builtin_amdgcn_permlane16_swap(r1[1], r1[0], false, false);
    x = (int)r2[0]; y = (int)r2[1];
}
__device__ __forceinline__ void pl32_pair(int &x, int &y) {
    u2 r1 = __builtin_amdgcn_permlane32_swap((unsigned)x, (unsigned)y, false, false);
    u2 r2 = __builtin_amdgcn_permlane32_swap(r1[1], r1[0], false, false);
    x = (int)r2[0]; y = (int)r2[1];
}

// ---- lane exchange by xor mask LM — R1 routing (proven fastest): DPP for
// 1..3 (zero-latency VALU), DS swizzle <32, bpermute >=32. DS keeps the
// exchange OFF the VALU; its latency is hidden by the other element's FMA
// stream (dual-chain design, this round). --------------------------------
template<int LM>
__device__ __forceinline__ v2f xlane(v2f v, int baddr) {
    if constexpr (LM == 0) return v;
    int x = f2i(v.x), y = f2i(v.y);
    if constexpr (LM == 1)       { x = dppm<177>(x); y = dppm<177>(y); }
    else if constexpr (LM == 2)  { x = dppm<78>(x);  y = dppm<78>(y); }
    else if constexpr (LM == 3)  { x = dppm<27>(x);  y = dppm<27>(y); }
    else if constexpr (LM < 32) {
        constexpr int off = (LM << 10) | 0x1F;   // BitMode xor
        x = __builtin_amdgcn_ds_swizzle(x, off);
        y = __builtin_amdgcn_ds_swizzle(y, off);
    } else {
        x = __builtin_amdgcn_ds_bpermute(baddr, x);
        y = __builtin_amdgcn_ds_bpermute(baddr, y);
    }
    return (v2f){ i2f(x), i2f(y) };
}

// Dual-element single-qubit gate (masks/parities verified R2-R11; dual-chain
// structure: xch-e0 -> coef fuse -> xch-e1 -> FMA-e0 -> FMA-e1 so each
// element's DS latency hides under the other's FMA block).
template<int MASK, int RMASK>
__device__ __forceinline__ void apply_gate2(v2f (&a0)[16], v2f (&a1)[16],
                                            float4 r0, float4 r1,
                                            float cqA, float sqA,
                                            float cqB, float sqB, int lane)
{
    constexpr int LM = (MASK >> 4) & 63;
    constexpr int JM = MASK & 15;
    constexpr int RH = (RMASK >> 4) & 63;
    constexpr int RL = RMASK & 15;

    const int baddr = ((lane ^ LM) << 2);

    // exchange e0 (DS ops go in flight first)
    v2f o0[16];
    #pragma unroll
    for (int j = 0; j < 16; ++j) o0[j] = xlane<LM>(a0[j ^ JM], baddr);

    // fuse Rot * RY(c,s) for both elements (overlaps e0's DS latency)
    const v2f r0a = { r0.x, r0.y }, r0b = { r0.z, r0.w };
    const v2f r1a = { r1.x, r1.y }, r1b = { r1.z, r1.w };
    const bool lp = (RH != 0) && (__popc(lane & RH) & 1);

    const v2f vcsA = { cqA, sqA };
    const v2f g00A = pk_ab  (r0a, r0b, vcsA);
    const v2f g01A = pk_ab_n(r0b, r0a, vcsA);
    const v2f g10A = pk_ab  (r1a, r1b, vcsA);
    const v2f g11A = pk_ab_n(r1b, r1a, vcsA);
    const v2f A0A = lp ? g11A : g00A;
    const v2f B0A = lp ? g10A : g01A;
    const v2f A1A = lp ? g00A : g11A;
    const v2f B1A = lp ? g01A : g10A;

    const v2f vcsB = { cqB, sqB };
    const v2f g00B = pk_ab  (r0a, r0b, vcsB);
    const v2f g01B = pk_ab_n(r0b, r0a, vcsB);
    const v2f g10B = pk_ab  (r1a, r1b, vcsB);
    const v2f g11B = pk_ab_n(r1b, r1a, vcsB);
    const v2f A0B = lp ? g11B : g00B;
    const v2f B0B = lp ? g10B : g01B;
    const v2f A1B = lp ? g00B : g11B;
    const v2f B1B = lp ? g01B : g10B;

    // exchange e1 (in flight while FMA-e0 runs)
    v2f o1[16];
    #pragma unroll
    for (int j = 0; j < 16; ++j) o1[j] = xlane<LM>(a1[j ^ JM], baddr);

    // new = A (x) a + B (x) o (complex), 4 VOP3P per amp, IEEE order preserved
#define QNN_F(ARR, OARR, A0_, A1_, B0_, B1_, J) {                             \
    constexpr int SP_ = __builtin_popcount((J) & RL) & 1;                     \
    const v2f CA = SP_ ? A1_ : A0_;                                           \
    const v2f CB = SP_ ? B1_ : B0_;                                           \
    const v2f av = ARR[J]; const v2f ov = OARR[J];                            \
    v2f d;                                                                    \
    asm("v_pk_mul_f32 %0, %1, %2 op_sel:[0,0] op_sel_hi:[0,1]"                \
        : "=v"(d) : "v"(CA), "v"(av));          /* (Ar*ar, Ar*ai) */          \
    asm("v_pk_fma_f32 %0, %1, %2, %0 op_sel:[1,1,0] op_sel_hi:[1,0,1] neg_lo:[0,1,0]" \
        : "+v"(d) : "v"(CA), "v"(av));          /* (-Ai*ai, +Ai*ar) */        \
    asm("v_pk_fma_f32 %0, %1, %2, %0 op_sel:[0,0,0] op_sel_hi:[0,1,1]"        \
        : "+v"(d) : "v"(CB), "v"(ov));          /* (+Br*pr, +Br*pi) */        \
    asm("v_pk_fma_f32 %0, %1, %2, %0 op_sel:[1,1,0] op_sel_hi:[1,0,1] neg_lo:[0,1,0]" \
        : "+v"(d) : "v"(CB), "v"(ov));          /* (-Bi*pi, +Bi*pr) */        \
    ARR[J] = d; }
#define FMA16(ARR, OARR, A0_, A1_, B0_, B1_)                                  \
    QNN_F(ARR,OARR,A0_,A1_,B0_,B1_,0)  QNN_F(ARR,OARR,A0_,A1_,B0_,B1_,1)      \
    QNN_F(ARR,OARR,A0_,A1_,B0_,B1_,2)  QNN_F(ARR,OARR,A0_,A1_,B0_,B1_,3)      \
    QNN_F(ARR,OARR,A0_,A1_,B0_,B1_,4)  QNN_F(ARR,OARR,A0_,A1_,B0_,B1_,5)      \
    QNN_F(ARR,OARR,A0_,A1_,B0_,B1_,6)  QNN_F(ARR,OARR,A0_,A1_,B0_,B1_,7)      \
    QNN_F(ARR,OARR,A0_,A1_,B0_,B1_,8)  QNN_F(ARR,OARR,A0_,A1_,B0_,B1_,9)      \
    QNN_F(ARR,OARR,A0_,A1_,B0_,B1_,10) QNN_F(ARR,OARR,A0_,A1_,B0_,B1_,11)     \
    QNN_F(ARR,OARR,A0_,A1_,B0_,B1_,12) QNN_F(ARR,OARR,A0_,A1_,B0_,B1_,13)     \
    QNN_F(ARR,OARR,A0_,A1_,B0_,B1_,14) QNN_F(ARR,OARR,A0_,A1_,B0_,B1_,15)

    FMA16(a0, o0, A0A, A1A, B0A, B1A)
    FMA16(a1, o1, A0B, A1B, B0B, B1B)
#undef FMA16
#undef QNN_F
}

// ---- layer 1 analytic: product state amp[p] = prod_q col0(G_q)[bit_q(p)] ----
__device__ __forceinline__ void layer1(v2f (&a)[16], const float (&c_)[NQ],
                                       const float (&s_)[NQ],
                                       const float4 (*rot)[2], int lane)
{
    v2f c0[4], c1[4];
    v2f Ln = {1.f, 0.f};
    #pragma unroll
    for (int q = 0; q < NQ; ++q) {
        float4 r0 = rot[q][0], r1 = rot[q][1];
        const v2f vcs = { c_[q], s_[q] };
        const v2f r0a = { r0.x, r0.y }, r0b = { r0.z, r0.w };
        const v2f r1a = { r1.x, r1.y }, r1b = { r1.z, r1.w };
        v2f g0 = pk_ab(r0a, r0b, vcs);
        v2f g1 = pk_ab(r1a, r1b, vcs);
        if (q < 4) { c0[q] = g0; c1[q] = g1; }
        else {
            v2f gg = ((lane >> (q - 4)) & 1) ? g1 : g0;
            Ln = (q == 4) ? gg : cmul(Ln, gg);
        }
    }
    v2f S01[4], SH[4];
    #pragma unroll
    for (int j = 0; j < 4; ++j)
        S01[j] = cmul((j & 1) ? c1[0] : c0[0], (j & 2) ? c1[1] : c0[1]);
    #pragma unroll
    for (int h = 0; h < 4; ++h)
        SH[h] = cmul(cmul((h & 1) ? c1[2] : c0[2], (h & 2) ? c1[3] : c0[3]), Ln);
    #pragma unroll
    for (int j = 0; j < 16; ++j)
        a[j] = cmul(S01[j & 3], SH[j >> 2]);
}

__global__ __launch_bounds__(256, 2)
void qnn_kernel(const float* __restrict__ x, const float* __restrict__ w,
                float* __restrict__ out)
{
    __shared__ float4 rotL[NL * NQ][2];   // (R00,R01) | (R10,R11)

    const int t    = threadIdx.x;
    const int lane = t & 63;
    const int wv   = blockIdx.x * 4 + (t >> 6);   // wave -> TWO batch elements

    if (t < NL * NQ) {
        const float* wp = w + t * 3;
        float phi = wp[0], th = wp[1], om = wp[2];
        float ct = cosf(th * 0.5f), st = sinf(th * 0.5f);
        float ap = (phi + om) * 0.5f, am = (phi - om) * 0.5f;
        float cap = cosf(ap), sap = sinf(ap);
        float cam = cosf(am), sam = sinf(am);
        rotL[t][0] = make_float4(cap * ct, -sap * ct, -cam * st, -sam * st);
        rotL[t][1] = make_float4(cam * st, -sam * st,  cap * ct,  sap * ct);
    }
    __syncthreads();

    // ---- per-batch RY cos/sin for both elements (wave-uniform -> SGPR) ----
    const float* xb = x + (size_t)__builtin_amdgcn_readfirstlane(wv * 2 * NQ);
    float cA[NQ], sA[NQ], cB[NQ], sB[NQ];
    #pragma unroll
    for (int q = 0; q < NQ; ++q) {
        float xv = xb[q] * 0.5f;
        cA[q] = i2f(__builtin_amdgcn_readfirstlane(f2i(__cosf(xv))));
        sA[q] = i2f(__builtin_amdgcn_readfirstlane(f2i(__sinf(xv))));
        float xw = xb[NQ + q] * 0.5f;
        cB[q] = i2f(__builtin_amdgcn_readfirstlane(f2i(__cosf(xw))));
        sB[q] = i2f(__builtin_amdgcn_readfirstlane(f2i(__sinf(xw))));
    }

    v2f a0[16], a1[16];
    layer1(a0, cA, sA, rotL, lane);
    layer1(a1, cB, sB, rotL, lane);

    // ---- layers 2..3 (masks + parities verified in R2/R3/R5/R8) ----
#define GATE(IDX, Q, MASK, RMASK)                                             \
    apply_gate2<MASK, RMASK>(a0, a1, rotL[IDX][0], rotL[IDX][1],              \
                             cA[Q], sA[Q], cB[Q], sB[Q], lane);
    GATE(10, 0, 0x003, 0x3FE)  GATE(11, 1, 0x006, 0x003)
    GATE(12, 2, 0x00C, 0x007)  GATE(13, 3, 0x018, 0x00F)
    GATE(14, 4, 0x030, 0x01F)  GATE(15, 5, 0x060, 0x03F)
    GATE(16, 6, 0x0C0, 0x07F)  GATE(17, 7, 0x180, 0x0FF)
    GATE(18, 8, 0x300, 0x1FF)  GATE(19, 9, 0x203, 0x3FF)
    GATE(20, 0, 0x005, 0x2AB)  GATE(21, 1, 0x00A, 0x3FD)
    GATE(22, 2, 0x014, 0x3FA)  GATE(23, 3, 0x028, 0x3F5)
    GATE(24, 4, 0x050, 0x3EA)  GATE(25, 5, 0x0A0, 0x3D5)
    GATE(26, 6, 0x140, 0x3AA)  GATE(27, 7, 0x280, 0x355)
    GATE(28, 8, 0x103, 0x2AA)  GATE(29, 9, 0x206, 0x155)
#undef GATE

    // ---- probabilities (element pair packed in v2f) + packed 4-bit WH ----
    v2f P[16];
    #pragma unroll
    for (int j = 0; j < 16; ++j)
        P[j] = (v2f){ fmaf(a0[j].x, a0[j].x, a0[j].y * a0[j].y),
                      fmaf(a1[j].x, a1[j].x, a1[j].y * a1[j].y) };
    #pragma unroll
    for (int bit = 0; bit < 4; ++bit) {
        #pragma unroll
        for (int j = 0; j < 16; ++j)
            if (!(j & (1 << bit))) {
                int k = j | (1 << bit);
                v2f u = P[j], v = P[k];
                P[j] = u + v;     // v_pk_add_f32
                P[k] = u - v;
            }
    }

    v2f vout = {0.f, 0.f};
#define MEAS(Q, RM)                                                           \
    { constexpr int RH_ = ((RM) >> 4) & 63;                                   \
      constexpr int RL_ = (RM) & 15;                                          \
      v2f v = P[RL_];                                                         \
      if (__popc(lane & RH_) & 1) v = -v;                                     \
      v2f tt;                                                                 \
      tt.x = i2f(dppm<177>(f2i(v.x))); tt.y = i2f(dppm<177>(f2i(v.y)));       \
      v += tt;                                   /* xor1  */                  \
      tt.x = i2f(dppm<78>(f2i(v.x)));  tt.y = i2f(dppm<78>(f2i(v.y)));        \
      v += tt;                                   /* xor2  */                  \
      tt.x = i2f(dppm<321>(dppm<27>(f2i(v.x))));                              \
      tt.y = i2f(dppm<321>(dppm<27>(f2i(v.y))));                              \
      v += tt;                                   /* xor4 = 7^3 */             \
      tt.x = i2f(dppm<320>(dppm<321>(f2i(v.x))));                             \
      tt.y = i2f(dppm<320>(dppm<321>(f2i(v.y))));                             \
      v += tt;                                   /* xor8 = 15^7 */            \
      { int px = f2i(v.x), py = f2i(v.y); pl16_pair(px, py);                  \
        tt = (v2f){ i2f(px), i2f(py) }; }                                     \
      v += tt;                                   /* xor16 (pair trick) */     \
      { int px = f2i(v.x), py = f2i(v.y); pl32_pair(px, py);                  \
        tt = (v2f){ i2f(px), i2f(py) }; }                                     \
      v += tt;                                   /* xor32 (pair trick) */     \
      if (lane == (Q)) vout = v; }
    MEAS(0, 0x0CD) MEAS(1, 0x156) MEAS(2, 0x2AC) MEAS(3, 0x159)
    MEAS(4, 0x2B3) MEAS(5, 0x166) MEAS(6, 0x2CC) MEAS(7, 0x199)
    MEAS(8, 0x333) MEAS(9, 0x266)
#undef MEAS

    if (lane < NQ) {
        out[(wv * 2)     * NQ + lane] = vout.x;
        out[(wv * 2 + 1) * NQ + lane] = vout.y;
    }
}

extern "C" void kernel_launch(void* const* d_in, const int* in_sizes, int n_in,
                              void* d_out, int out_size, void* d_ws, size_t ws_size,
                              hipStream_t stream) {
    const float* x = (const float*)d_in[0];   // (4096, 10) f32
    const float* w = (const float*)d_in[1];   // (3, 10, 3) f32
    float* out = (float*)d_out;               // (4096, 10) f32
    const int B = in_sizes[0] / NQ;           // 4096
    qnn_kernel<<<B / 8, 256, 0, stream>>>(x, w, out);
}

// Round 5
// 76.950 us; speedup vs baseline: 1.0565x; 1.0052x over previous
//
#include <hip/hip_runtime.h>

#define NQ 10
#define NL 3

typedef float v2f __attribute__((ext_vector_type(2)));

__device__ __forceinline__ int   f2i(float v) { union { float f; int i; } u; u.f = v; return u.i; }
__device__ __forceinline__ float i2f(int v)   { union { int i; float f; } u; u.i = v; return u.f; }

// ---- packed-f32 complex helpers (gfx950 VOP3P; issue-slot savings — R0/R1
// proven). ----
__device__ __forceinline__ v2f cmul(v2f a, v2f b) {
    v2f d;
    asm("v_pk_mul_f32 %0, %1, %2 op_sel:[0,0] op_sel_hi:[0,1]"
        : "=v"(d) : "v"(a), "v"(b));                       // (ax*bx, ax*by)
    asm("v_pk_fma_f32 %0, %1, %2, %0 op_sel:[1,1,0] op_sel_hi:[1,0,1] neg_lo:[0,1,0]"
        : "+v"(d) : "v"(a), "v"(b));                       // (+= -ay*by, += ay*bx)
    return d;
}

// A*cs.x + B*cs.y elementwise
__device__ __forceinline__ v2f pk_ab(v2f A, v2f B, v2f cs) {
    v2f d;
    asm("v_pk_mul_f32 %0, %1, %2 op_sel:[0,1] op_sel_hi:[1,1]"
        : "=v"(d) : "v"(B), "v"(cs));                      // (B.x*s, B.y*s)
    asm("v_pk_fma_f32 %0, %1, %2, %0 op_sel:[0,0,0] op_sel_hi:[1,0,1]"
        : "+v"(d) : "v"(A), "v"(cs));                      // += (A.x*c, A.y*c)
    return d;
}
// A*cs.x - B*cs.y elementwise
__device__ __forceinline__ v2f pk_ab_n(v2f A, v2f B, v2f cs) {
    v2f d;
    asm("v_pk_mul_f32 %0, %1, %2 op_sel:[0,1] op_sel_hi:[1,1] neg_lo:[1,0] neg_hi:[1,0]"
        : "=v"(d) : "v"(B), "v"(cs));                      // (-B.x*s, -B.y*s)
    asm("v_pk_fma_f32 %0, %1, %2, %0 op_sel:[0,0,0] op_sel_hi:[1,0,1]"
        : "+v"(d) : "v"(A), "v"(cs));
    return d;
}

template<int C> __device__ __forceinline__ int dppm(int v) {
    return __builtin_amdgcn_mov_dpp(v, C, 0xF, 0xF, false);
}

// ---- lane exchange by xor mask LM.
// R4 post-mortem: per-CU DS pipe (~12 cyc/permute-op, 16 waves sharing) is
// the modeled limiter; VALU issue is only ~25% of runtime. So: route every
// mask reachable by a SHORT mov_dpp chain on the VALU (zero-latency,
// hazard-free, R1/R3-verified correct), DS only for the rest.
//   DPP set: xor1=177, xor2=78, xor3=27, xor7=321(row_half_mirror),
//            xor15=320(row_mirror); compositions 5=2^7, 6=1^7, 10=2^7^15,
//            12=3^15 (correctness proven on HW in R3 run).
// Gates moved off DS this round: LM=5,6,10,12 (DS ops/wave 352 -> 224).
// Permlane (R3's regression) deliberately NOT used. ----
template<int LM>
__device__ __forceinline__ v2f xlane(v2f v, int baddr) {
    if constexpr (LM == 0) return v;
    int x = f2i(v.x), y = f2i(v.y);
    if constexpr (LM == 1)       { x = dppm<177>(x); y = dppm<177>(y); }
    else if constexpr (LM == 2)  { x = dppm<78>(x);  y = dppm<78>(y); }
    else if constexpr (LM == 3)  { x = dppm<27>(x);  y = dppm<27>(y); }
    else if constexpr (LM == 5)  { x = dppm<321>(dppm<78>(x));
                                   y = dppm<321>(dppm<78>(y)); }
    else if constexpr (LM == 6)  { x = dppm<321>(dppm<177>(x));
                                   y = dppm<321>(dppm<177>(y)); }
    else if constexpr (LM == 10) { x = dppm<320>(dppm<321>(dppm<78>(x)));
                                   y = dppm<320>(dppm<321>(dppm<78>(y))); }
    else if constexpr (LM == 12) { x = dppm<320>(dppm<27>(x));
                                   y = dppm<320>(dppm<27>(y)); }
    else if constexpr (LM < 32) {
        constexpr int off = (LM << 10) | 0x1F;   // BitMode xor
        x = __builtin_amdgcn_ds_swizzle(x, off);
        y = __builtin_amdgcn_ds_swizzle(y, off);
    } else {
        x = __builtin_amdgcn_ds_bpermute(baddr, x);
        y = __builtin_amdgcn_ds_bpermute(baddr, y);
    }
    return (v2f){ i2f(x), i2f(y) };
}

// Generalized single-qubit gate under GF(2) index transform (masks verified
// R2-R11). Packed-f32 math: 4 VOP3P per amp, identical IEEE rounding order.
// Slot parity SP is compile-time so coefficient choice is free.
template<int MASK, int RMASK>
__device__ __forceinline__ void apply_gate(v2f (&a)[16], float4 r0, float4 r1,
                                           float cq, float sq, int lane)
{
    constexpr int LM = (MASK >> 4) & 63;
    constexpr int JM = MASK & 15;
    constexpr int RH = (RMASK >> 4) & 63;
    constexpr int RL = RMASK & 15;

    // fuse Rot * RY(c,s): 8 packed instr
    const v2f vcs = { cq, sq };
    const v2f r0a = { r0.x, r0.y }, r0b = { r0.z, r0.w };
    const v2f r1a = { r1.x, r1.y }, r1b = { r1.z, r1.w };
    const v2f g00 = pk_ab  (r0a, r0b, vcs);   // (g00r, g00i)
    const v2f g01 = pk_ab_n(r0b, r0a, vcs);   // (g01r, g01i)
    const v2f g10 = pk_ab  (r1a, r1b, vcs);
    const v2f g11 = pk_ab_n(r1b, r1a, vcs);

    const bool lp = (RH != 0) && (__popc(lane & RH) & 1);
    // parity-0 (total parity even) and parity-1 coefficient sets, (re,im) pairs
    const v2f A0 = lp ? g11 : g00;
    const v2f B0 = lp ? g10 : g01;
    const v2f A1 = lp ? g00 : g11;
    const v2f B1 = lp ? g01 : g10;

    const int baddr = ((lane ^ LM) << 2);

    // phase 1: all partner values (independent -> batched DS/DPP issue)
    v2f o[16];
    #pragma unroll
    for (int j = 0; j < 16; ++j) o[j] = xlane<LM>(a[j ^ JM], baddr);

    // phase 2: new = A (x) a + B (x) o (complex), 4 packed FMA-class instr/amp
#define QNN_F(J) { constexpr int SP_ = __builtin_popcount((J) & RL) & 1;      \
    const v2f CA = SP_ ? A1 : A0;                                             \
    const v2f CB = SP_ ? B1 : B0;                                             \
    const v2f av = a[J]; const v2f ov = o[J];                                 \
    v2f d;                                                                    \
    asm("v_pk_mul_f32 %0, %1, %2 op_sel:[0,0] op_sel_hi:[0,1]"                \
        : "=v"(d) : "v"(CA), "v"(av));          /* (Ar*ar, Ar*ai) */          \
    asm("v_pk_fma_f32 %0, %1, %2, %0 op_sel:[1,1,0] op_sel_hi:[1,0,1] neg_lo:[0,1,0]" \
        : "+v"(d) : "v"(CA), "v"(av));          /* (-Ai*ai, +Ai*ar) */        \
    asm("v_pk_fma_f32 %0, %1, %2, %0 op_sel:[0,0,0] op_sel_hi:[0,1,1]"        \
        : "+v"(d) : "v"(CB), "v"(ov));          /* (+Br*pr, +Br*pi) */        \
    asm("v_pk_fma_f32 %0, %1, %2, %0 op_sel:[1,1,0] op_sel_hi:[1,0,1] neg_lo:[0,1,0]" \
        : "+v"(d) : "v"(CB), "v"(ov));          /* (-Bi*pi, +Bi*pr) */        \
    a[J] = d; }
    QNN_F(0) QNN_F(1) QNN_F(2) QNN_F(3) QNN_F(4) QNN_F(5) QNN_F(6) QNN_F(7)
    QNN_F(8) QNN_F(9) QNN_F(10) QNN_F(11) QNN_F(12) QNN_F(13) QNN_F(14) QNN_F(15)
#undef QNN_F
}

__global__ __launch_bounds__(256, 4)
void qnn_kernel(const float* __restrict__ x, const float* __restrict__ w,
                float* __restrict__ out)
{
    __shared__ float4 rotL[NL * NQ][2];   // (R00,R01) | (R10,R11)

    const int t    = threadIdx.x;
    const int lane = t & 63;
    const int b    = blockIdx.x * 4 + (t >> 6);   // one wave per batch element

    if (t < NL * NQ) {
        const float* wp = w + t * 3;
        float phi = wp[0], th = wp[1], om = wp[2];
        float ct = cosf(th * 0.5f), st = sinf(th * 0.5f);
        float ap = (phi + om) * 0.5f, am = (phi - om) * 0.5f;
        float cap = cosf(ap), sap = sinf(ap);
        float cam = cosf(am), sam = sinf(am);
        rotL[t][0] = make_float4(cap * ct, -sap * ct, -cam * st, -sam * st);
        rotL[t][1] = make_float4(cam * st, -sam * st,  cap * ct,  sap * ct);
    }
    __syncthreads();

    // ---- per-batch RY cos/sin (wave-uniform -> SGPR via readfirstlane) ----
    const float* xb = x + (size_t)__builtin_amdgcn_readfirstlane(b * NQ);
    float c_[NQ], s_[NQ];
    #pragma unroll
    for (int q = 0; q < NQ; ++q) {
        float xv = xb[q] * 0.5f;
        c_[q] = i2f(__builtin_amdgcn_readfirstlane(f2i(__cosf(xv))));
        s_[q] = i2f(__builtin_amdgcn_readfirstlane(f2i(__sinf(xv))));
    }

    // ---- layer 1 analytic: product state amp[p] = prod_q col0(G_q)[bit_q(p)] ----
    v2f c0[4], c1[4];
    v2f Ln = {1.f, 0.f};
    #pragma unroll
    for (int q = 0; q < NQ; ++q) {
        float4 r0 = rotL[q][0], r1 = rotL[q][1];
        const v2f vcs = { c_[q], s_[q] };
        const v2f r0a = { r0.x, r0.y }, r0b = { r0.z, r0.w };
        const v2f r1a = { r1.x, r1.y }, r1b = { r1.z, r1.w };
        v2f g0 = pk_ab(r0a, r0b, vcs);
        v2f g1 = pk_ab(r1a, r1b, vcs);
        if (q < 4) { c0[q] = g0; c1[q] = g1; }
        else {
            v2f gg = ((lane >> (q - 4)) & 1) ? g1 : g0;
            Ln = (q == 4) ? gg : cmul(Ln, gg);
        }
    }
    v2f S01[4], SH[4];
    #pragma unroll
    for (int j = 0; j < 4; ++j)
        S01[j] = cmul((j & 1) ? c1[0] : c0[0], (j & 2) ? c1[1] : c0[1]);
    #pragma unroll
    for (int h = 0; h < 4; ++h)
        SH[h] = cmul(cmul((h & 1) ? c1[2] : c0[2], (h & 2) ? c1[3] : c0[3]), Ln);
    v2f a[16];
    #pragma unroll
    for (int j = 0; j < 16; ++j)
        a[j] = cmul(S01[j & 3], SH[j >> 2]);

    // ---- layers 2..3 (masks + parities verified in R2/R3/R5/R8) ----
#define GATE(IDX, Q, MASK, RMASK) \
    apply_gate<MASK, RMASK>(a, rotL[IDX][0], rotL[IDX][1], c_[Q], s_[Q], lane);
    GATE(10, 0, 0x003, 0x3FE)  GATE(11, 1, 0x006, 0x003)
    GATE(12, 2, 0x00C, 0x007)  GATE(13, 3, 0x018, 0x00F)
    GATE(14, 4, 0x030, 0x01F)  GATE(15, 5, 0x060, 0x03F)
    GATE(16, 6, 0x0C0, 0x07F)  GATE(17, 7, 0x180, 0x0FF)
    GATE(18, 8, 0x300, 0x1FF)  GATE(19, 9, 0x203, 0x3FF)
    GATE(20, 0, 0x005, 0x2AB)  GATE(21, 1, 0x00A, 0x3FD)
    GATE(22, 2, 0x014, 0x3FA)  GATE(23, 3, 0x028, 0x3F5)
    GATE(24, 4, 0x050, 0x3EA)  GATE(25, 5, 0x0A0, 0x3D5)
    GATE(26, 6, 0x140, 0x3AA)  GATE(27, 7, 0x280, 0x355)
    GATE(28, 8, 0x103, 0x2AA)  GATE(29, 9, 0x206, 0x155)
#undef GATE

    // ---- probabilities + 4-bit Walsh-Hadamard over slots ----
    float P[16];
    #pragma unroll
    for (int j = 0; j < 16; ++j)
        P[j] = fmaf(a[j].x, a[j].x, a[j].y * a[j].y);
    #pragma unroll
    for (int bit = 0; bit < 4; ++bit) {
        #pragma unroll
        for (int j = 0; j < 16; ++j)
            if (!(j & (1 << bit))) {
                int k = j | (1 << bit);
                float u = P[j], v = P[k];
                P[j] = u + v;
                P[k] = u - v;
            }
    }

    const int bp32 = ((lane ^ 32) << 2);
    float vout = 0.f;
#define MEAS(Q, RM)                                                           \
    { constexpr int RH_ = ((RM) >> 4) & 63;                                   \
      constexpr int RL_ = (RM) & 15;                                          \
      float v = P[RL_];                                                       \
      if (__popc(lane & RH_) & 1) v = -v;                                     \
      v += i2f(dppm<177>(f2i(v)));                 /* xor1  */                \
      v += i2f(dppm<78>(f2i(v)));                  /* xor2  */                \
      v += i2f(dppm<321>(dppm<27>(f2i(v))));       /* xor4 = 7^3 */           \
      v += i2f(dppm<320>(dppm<321>(f2i(v))));      /* xor8 = 15^7 */          \
      v += i2f(__builtin_amdgcn_ds_swizzle(f2i(v), (16 << 10) | 0x1F));       \
      v += i2f(__builtin_amdgcn_ds_bpermute(bp32, f2i(v)));                   \
      if (lane == (Q)) vout = v; }
    MEAS(0, 0x0CD) MEAS(1, 0x156) MEAS(2, 0x2AC) MEAS(3, 0x159)
    MEAS(4, 0x2B3) MEAS(5, 0x166) MEAS(6, 0x2CC) MEAS(7, 0x199)
    MEAS(8, 0x333) MEAS(9, 0x266)
#undef MEAS

    if (lane < NQ) out[b * NQ + lane] = vout;
}

extern "C" void kernel_launch(void* const* d_in, const int* in_sizes, int n_in,
                              void* d_out, int out_size, void* d_ws, size_t ws_size,
                              hipStream_t stream) {
    const float* x = (const float*)d_in[0];   // (4096, 10) f32
    const float* w = (const float*)d_in[1];   // (3, 10, 3) f32
    float* out = (float*)d_out;               // (4096, 10) f32
    const int B = in_sizes[0] / NQ;           // 4096
    qnn_kernel<<<B / 4, 256, 0, stream>>>(x, w, out);
}

// Round 7
// 76.722 us; speedup vs baseline: 1.0597x; 1.0030x over previous
//
#include <hip/hip_runtime.h>

#define NQ 10
#define NL 3

typedef float v2f __attribute__((ext_vector_type(2)));

__device__ __forceinline__ int   f2i(float v) { union { float f; int i; } u; u.f = v; return u.i; }
__device__ __forceinline__ float i2f(int v)   { union { int i; float f; } u; u.i = v; return u.f; }
__device__ __forceinline__ v2f   sp(float f)  { return (v2f){ f, f }; }

template<int C> __device__ __forceinline__ int dppm(int v) {
    return __builtin_amdgcn_mov_dpp(v, C, 0xF, 0xF, false);
}

// ---- R7: element-pair packing (e0,e1) per register, ALL math in plain C
// (compiler-scheduled; no hand asm — R2/R6 lesson: every failure coincided
// with new unverified inline-asm forms; bf16 output gives 8x rounding
// headroom so asm-controlled IEEE order is unnecessary). Exchange routing =
// R1-proven builtins only. ----

// lane exchange by xor mask LM: DPP for 1..3, ds_swizzle <32, bpermute >=32
template<int LM>
__device__ __forceinline__ v2f xlane(v2f v, int baddr) {
    if constexpr (LM == 0) return v;
    int x = f2i(v.x), y = f2i(v.y);
    if constexpr (LM == 1)       { x = dppm<177>(x); y = dppm<177>(y); }
    else if constexpr (LM == 2)  { x = dppm<78>(x);  y = dppm<78>(y); }
    else if constexpr (LM == 3)  { x = dppm<27>(x);  y = dppm<27>(y); }
    else if constexpr (LM < 32) {
        constexpr int off = (LM << 10) | 0x1F;   // BitMode xor
        x = __builtin_amdgcn_ds_swizzle(x, off);
        y = __builtin_amdgcn_ds_swizzle(y, off);
    } else {
        x = __builtin_amdgcn_ds_bpermute(baddr, x);
        y = __builtin_amdgcn_ds_bpermute(baddr, y);
    }
    return (v2f){ i2f(x), i2f(y) };
}

// complex over element-pairs: re=(re0,re1), im=(im0,im1)
struct cpx { v2f re, im; };
__device__ __forceinline__ cpx cm(cpx a, cpx b) {
    cpx r;
    r.re = a.re * b.re - a.im * b.im;
    r.im = a.re * b.im + a.im * b.re;
    return r;
}

// Dual-element single-qubit gate under GF(2) index transform (masks verified
// R2-R11, unchanged). One coefficient fuse serves both elements.
template<int MASK, int RMASK>
__device__ __forceinline__ void apply_gate(v2f (&re)[16], v2f (&im)[16],
                                           float4 r0, float4 r1,
                                           v2f C, v2f S, int lane)
{
    constexpr int LM = (MASK >> 4) & 63;
    constexpr int JM = MASK & 15;
    constexpr int RH = (RMASK >> 4) & 63;
    constexpr int RL = RMASK & 15;

    const int baddr = ((lane ^ LM) << 2);

    // phase 1: partner values (DS/DPP batched; latency overlaps coef fuse)
    v2f ore[16], oim[16];
    #pragma unroll
    for (int j = 0; j < 16; ++j) ore[j] = xlane<LM>(re[j ^ JM], baddr);
    #pragma unroll
    for (int j = 0; j < 16; ++j) oim[j] = xlane<LM>(im[j ^ JM], baddr);

    // fuse Rot * RY(c,s) once for both elements
    const v2f G00R = sp(r0.x) * C + sp(r0.z) * S;
    const v2f G00I = sp(r0.y) * C + sp(r0.w) * S;
    const v2f G01R = sp(r0.z) * C - sp(r0.x) * S;
    const v2f G01I = sp(r0.w) * C - sp(r0.y) * S;
    const v2f G10R = sp(r1.x) * C + sp(r1.z) * S;
    const v2f G10I = sp(r1.y) * C + sp(r1.w) * S;
    const v2f G11R = sp(r1.z) * C - sp(r1.x) * S;
    const v2f G11I = sp(r1.w) * C - sp(r1.y) * S;

    const bool lp = (RH != 0) && (__popc(lane & RH) & 1);
    const v2f A0R = lp ? G11R : G00R, A0I = lp ? G11I : G00I;
    const v2f B0R = lp ? G10R : G01R, B0I = lp ? G10I : G01I;
    const v2f A1R = lp ? G00R : G11R, A1I = lp ? G00I : G11I;
    const v2f B1R = lp ? G01R : G10R, B1I = lp ? G01I : G10I;

    // phase 2: new = A (x) a + B (x) o (complex), both elements per op
#define QNN_F(J) { constexpr int SP_ = __builtin_popcount((J) & RL) & 1;      \
    const v2f CAR = SP_ ? A1R : A0R, CAI = SP_ ? A1I : A0I;                   \
    const v2f CBR = SP_ ? B1R : B0R, CBI = SP_ ? B1I : B0I;                   \
    const v2f ar = re[J], ai = im[J], pr = ore[J], pi = oim[J];               \
    re[J] = CAR * ar - CAI * ai + CBR * pr - CBI * pi;                        \
    im[J] = CAR * ai + CAI * ar + CBR * pi + CBI * pr; }
    QNN_F(0) QNN_F(1) QNN_F(2) QNN_F(3) QNN_F(4) QNN_F(5) QNN_F(6) QNN_F(7)
    QNN_F(8) QNN_F(9) QNN_F(10) QNN_F(11) QNN_F(12) QNN_F(13) QNN_F(14) QNN_F(15)
#undef QNN_F
}

__global__ __launch_bounds__(256, 2)
void qnn_kernel(const float* __restrict__ x, const float* __restrict__ w,
                float* __restrict__ out)
{
    __shared__ float4 rotL[NL * NQ][2];   // (R00,R01) | (R10,R11)

    const int t    = threadIdx.x;
    const int lane = t & 63;
    const int wv   = blockIdx.x * 4 + (t >> 6);   // wave -> elements 2wv, 2wv+1

    if (t < NL * NQ) {
        const float* wp = w + t * 3;
        float phi = wp[0], th = wp[1], om = wp[2];
        float ct = cosf(th * 0.5f), st = sinf(th * 0.5f);
        float ap = (phi + om) * 0.5f, am = (phi - om) * 0.5f;
        float cap = cosf(ap), sap = sinf(ap);
        float cam = cosf(am), sam = sinf(am);
        rotL[t][0] = make_float4(cap * ct, -sap * ct, -cam * st, -sam * st);
        rotL[t][1] = make_float4(cam * st, -sam * st,  cap * ct,  sap * ct);
    }
    __syncthreads();

    // ---- per-batch RY cos/sin pairs (wave-uniform values) ----
    const float* xb = x + (size_t)(wv * 2 * NQ);
    v2f C_[NQ], S_[NQ];
    #pragma unroll
    for (int q = 0; q < NQ; ++q) {
        float x0 = xb[q] * 0.5f, x1 = xb[NQ + q] * 0.5f;
        C_[q] = (v2f){ __cosf(x0), __cosf(x1) };
        S_[q] = (v2f){ __sinf(x0), __sinf(x1) };
    }

    // ---- layer 1 analytic: product state, both elements at once ----
    v2f re[16], im[16];
    {
        cpx c0[4], c1[4], Ln;
        #pragma unroll
        for (int q = 0; q < NQ; ++q) {
            float4 r0 = rotL[q][0], r1v = rotL[q][1];
            cpx g0, g1;
            g0.re = sp(r0.x) * C_[q] + sp(r0.z) * S_[q];
            g0.im = sp(r0.y) * C_[q] + sp(r0.w) * S_[q];
            g1.re = sp(r1v.x) * C_[q] + sp(r1v.z) * S_[q];
            g1.im = sp(r1v.y) * C_[q] + sp(r1v.w) * S_[q];
            if (q < 4) { c0[q] = g0; c1[q] = g1; }
            else {
                const bool bit = (lane >> (q - 4)) & 1;
                cpx gg; gg.re = bit ? g1.re : g0.re; gg.im = bit ? g1.im : g0.im;
                Ln = (q == 4) ? gg : cm(Ln, gg);
            }
        }
        cpx S01[4], SH[4];
        #pragma unroll
        for (int j = 0; j < 4; ++j)
            S01[j] = cm((j & 1) ? c1[0] : c0[0], (j & 2) ? c1[1] : c0[1]);
        #pragma unroll
        for (int h = 0; h < 4; ++h)
            SH[h] = cm(cm((h & 1) ? c1[2] : c0[2], (h & 2) ? c1[3] : c0[3]), Ln);
        #pragma unroll
        for (int j = 0; j < 16; ++j) {
            cpx A = cm(S01[j & 3], SH[j >> 2]);
            re[j] = A.re; im[j] = A.im;
        }
    }

    // ---- layers 2..3 (masks + parities verified in R2/R3/R5/R8) ----
#define GATE(IDX, Q, MASK, RMASK)                                             \
    apply_gate<MASK, RMASK>(re, im, rotL[IDX][0], rotL[IDX][1],               \
                            C_[Q], S_[Q], lane);
    GATE(10, 0, 0x003, 0x3FE)  GATE(11, 1, 0x006, 0x003)
    GATE(12, 2, 0x00C, 0x007)  GATE(13, 3, 0x018, 0x00F)
    GATE(14, 4, 0x030, 0x01F)  GATE(15, 5, 0x060, 0x03F)
    GATE(16, 6, 0x0C0, 0x07F)  GATE(17, 7, 0x180, 0x0FF)
    GATE(18, 8, 0x300, 0x1FF)  GATE(19, 9, 0x203, 0x3FF)
    GATE(20, 0, 0x005, 0x2AB)  GATE(21, 1, 0x00A, 0x3FD)
    GATE(22, 2, 0x014, 0x3FA)  GATE(23, 3, 0x028, 0x3F5)
    GATE(24, 4, 0x050, 0x3EA)  GATE(25, 5, 0x0A0, 0x3D5)
    GATE(26, 6, 0x140, 0x3AA)  GATE(27, 7, 0x280, 0x355)
    GATE(28, 8, 0x103, 0x2AA)  GATE(29, 9, 0x206, 0x155)
#undef GATE

    // ---- probabilities + 4-bit Walsh-Hadamard (both elements packed) ----
    v2f P[16];
    #pragma unroll
    for (int j = 0; j < 16; ++j)
        P[j] = re[j] * re[j] + im[j] * im[j];
    #pragma unroll
    for (int bit = 0; bit < 4; ++bit) {
        #pragma unroll
        for (int j = 0; j < 16; ++j)
            if (!(j & (1 << bit))) {
                int k = j | (1 << bit);
                v2f u = P[j], v = P[k];
                P[j] = u + v;
                P[k] = u - v;
            }
    }

    const int bp32 = ((lane ^ 32) << 2);
    v2f vout = {0.f, 0.f};
#define MEAS(Q, RM)                                                           \
    { constexpr int RH_ = ((RM) >> 4) & 63;                                   \
      constexpr int RL_ = (RM) & 15;                                          \
      v2f v = P[RL_];                                                         \
      if (__popc(lane & RH_) & 1) v = -v;                                     \
      v2f tt;                                                                 \
      tt.x = i2f(dppm<177>(f2i(v.x))); tt.y = i2f(dppm<177>(f2i(v.y)));       \
      v += tt;                                   /* xor1  */                  \
      tt.x = i2f(dppm<78>(f2i(v.x)));  tt.y = i2f(dppm<78>(f2i(v.y)));        \
      v += tt;                                   /* xor2  */                  \
      tt.x = i2f(dppm<321>(dppm<27>(f2i(v.x))));                              \
      tt.y = i2f(dppm<321>(dppm<27>(f2i(v.y))));                              \
      v += tt;                                   /* xor4 = 7^3 */             \
      tt.x = i2f(dppm<320>(dppm<321>(f2i(v.x))));                             \
      tt.y = i2f(dppm<320>(dppm<321>(f2i(v.y))));                             \
      v += tt;                                   /* xor8 = 15^7 */            \
      tt.x = i2f(__builtin_amdgcn_ds_swizzle(f2i(v.x), (16 << 10) | 0x1F));   \
      tt.y = i2f(__builtin_amdgcn_ds_swizzle(f2i(v.y), (16 << 10) | 0x1F));   \
      v += tt;                                   /* xor16 */                  \
      tt.x = i2f(__builtin_amdgcn_ds_bpermute(bp32, f2i(v.x)));               \
      tt.y = i2f(__builtin_amdgcn_ds_bpermute(bp32, f2i(v.y)));               \
      v += tt;                                   /* xor32 */                  \
      if (lane == (Q)) vout = v; }
    MEAS(0, 0x0CD) MEAS(1, 0x156) MEAS(2, 0x2AC) MEAS(3, 0x159)
    MEAS(4, 0x2B3) MEAS(5, 0x166) MEAS(6, 0x2CC) MEAS(7, 0x199)
    MEAS(8, 0x333) MEAS(9, 0x266)
#undef MEAS

    if (lane < NQ) {
        out[(wv * 2)     * NQ + lane] = vout.x;
        out[(wv * 2 + 1) * NQ + lane] = vout.y;
    }
}

extern "C" void kernel_launch(void* const* d_in, const int* in_sizes, int n_in,
                              void* d_out, int out_size, void* d_ws, size_t ws_size,
                              hipStream_t stream) {
    const float* x = (const float*)d_in[0];   // (4096, 10) f32
    const float* w = (const float*)d_in[1];   // (3, 10, 3) f32
    float* out = (float*)d_out;               // (4096, 10) f32
    const int B = in_sizes[0] / NQ;           // 4096
    qnn_kernel<<<B / 8, 256, 0, stream>>>(x, w, out);
}

// Round 8
// 75.952 us; speedup vs baseline: 1.0704x; 1.0101x over previous
//
#include <hip/hip_runtime.h>

#define NQ 10
#define NL 3

typedef float v2f __attribute__((ext_vector_type(2)));

__device__ __forceinline__ int   f2i(float v) { union { float f; int i; } u; u.f = v; return u.i; }
__device__ __forceinline__ float i2f(int v)   { union { int i; float f; } u; u.i = v; return u.f; }
__device__ __forceinline__ v2f   sp(float f)  { return (v2f){ f, f }; }
// uniformize a wave-uniform float into SGPR (R1-proven pattern)
__device__ __forceinline__ float uf(float v) {
    return i2f(__builtin_amdgcn_readfirstlane(f2i(v)));
}
// elementwise fma on the element-pair vector -> llvm.fma.v2f32 -> v_pk_fma_f32
__device__ __forceinline__ v2f fmav(v2f a, v2f b, v2f c) {
    return __builtin_elementwise_fma(a, b, c);
}

template<int C> __device__ __forceinline__ int dppm(int v) {
    return __builtin_amdgcn_mov_dpp(v, C, 0xF, 0xF, false);
}

// ---- R8: element-pair packing (e0,e1) per register; ALL math via
// compiler-visible elementwise-fma builtins (forces v_pk_fma_f32 codegen,
// which R7's plain expressions did not reliably produce). No new inline asm
// (R2/R6 lesson). Exchange routing = R1-proven builtins. ----

// lane exchange by xor mask LM: DPP for 1..3, ds_swizzle <32, bpermute >=32
template<int LM>
__device__ __forceinline__ v2f xlane(v2f v, int baddr) {
    if constexpr (LM == 0) return v;
    int x = f2i(v.x), y = f2i(v.y);
    if constexpr (LM == 1)       { x = dppm<177>(x); y = dppm<177>(y); }
    else if constexpr (LM == 2)  { x = dppm<78>(x);  y = dppm<78>(y); }
    else if constexpr (LM == 3)  { x = dppm<27>(x);  y = dppm<27>(y); }
    else if constexpr (LM < 32) {
        constexpr int off = (LM << 10) | 0x1F;   // BitMode xor
        x = __builtin_amdgcn_ds_swizzle(x, off);
        y = __builtin_amdgcn_ds_swizzle(y, off);
    } else {
        x = __builtin_amdgcn_ds_bpermute(baddr, x);
        y = __builtin_amdgcn_ds_bpermute(baddr, y);
    }
    return (v2f){ i2f(x), i2f(y) };
}

// complex over element-pairs: re=(re0,re1), im=(im0,im1)
struct cpx { v2f re, im; };
__device__ __forceinline__ cpx cm(cpx a, cpx b) {
    cpx r;
    r.re = fmav(-a.im, b.im, a.re * b.re);
    r.im = fmav( a.im, b.re, a.re * b.im);
    return r;
}

// Dual-element single-qubit gate under GF(2) index transform (masks verified
// R2-R11, unchanged). One coefficient fuse serves both elements.
template<int MASK, int RMASK>
__device__ __forceinline__ void apply_gate(v2f (&re)[16], v2f (&im)[16],
                                           float4 r0, float4 r1,
                                           v2f C, v2f S, int lane)
{
    constexpr int LM = (MASK >> 4) & 63;
    constexpr int JM = MASK & 15;
    constexpr int RH = (RMASK >> 4) & 63;
    constexpr int RL = RMASK & 15;

    const int baddr = ((lane ^ LM) << 2);

    // phase 1: partner values (DS/DPP batched; latency overlaps coef fuse)
    v2f ore[16], oim[16];
    #pragma unroll
    for (int j = 0; j < 16; ++j) ore[j] = xlane<LM>(re[j ^ JM], baddr);
    #pragma unroll
    for (int j = 0; j < 16; ++j) oim[j] = xlane<LM>(im[j ^ JM], baddr);

    // fuse Rot * RY(c,s) once for both elements (2 pk ops per coefficient)
    const v2f G00R = fmav(sp(r0.x), C, sp(r0.z) * S);
    const v2f G00I = fmav(sp(r0.y), C, sp(r0.w) * S);
    const v2f G01R = fmav(sp(r0.z), C, sp(-r0.x) * S);
    const v2f G01I = fmav(sp(r0.w), C, sp(-r0.y) * S);
    const v2f G10R = fmav(sp(r1.x), C, sp(r1.z) * S);
    const v2f G10I = fmav(sp(r1.y), C, sp(r1.w) * S);
    const v2f G11R = fmav(sp(r1.z), C, sp(-r1.x) * S);
    const v2f G11I = fmav(sp(r1.w), C, sp(-r1.y) * S);

    const bool lp = (RH != 0) && (__popc(lane & RH) & 1);
    const v2f A0R = lp ? G11R : G00R, A0I = lp ? G11I : G00I;
    const v2f B0R = lp ? G10R : G01R, B0I = lp ? G10I : G01I;
    const v2f A1R = lp ? G00R : G11R, A1I = lp ? G00I : G11I;
    const v2f B1R = lp ? G01R : G10R, B1I = lp ? G01I : G10I;

    // phase 2: new = A (x) a + B (x) o (complex); 8 pk-fma-class ops per slot
    // update (re,im) of BOTH elements.
#define QNN_F(J) { constexpr int SP_ = __builtin_popcount((J) & RL) & 1;      \
    const v2f CAR = SP_ ? A1R : A0R, CAI = SP_ ? A1I : A0I;                   \
    const v2f CBR = SP_ ? B1R : B0R, CBI = SP_ ? B1I : B0I;                   \
    const v2f ar = re[J], ai = im[J], pr = ore[J], pi = oim[J];               \
    re[J] = fmav(-CBI, pi, fmav(CBR, pr, fmav(-CAI, ai, CAR * ar)));          \
    im[J] = fmav( CBI, pr, fmav(CBR, pi, fmav( CAI, ar, CAR * ai))); }
    QNN_F(0) QNN_F(1) QNN_F(2) QNN_F(3) QNN_F(4) QNN_F(5) QNN_F(6) QNN_F(7)
    QNN_F(8) QNN_F(9) QNN_F(10) QNN_F(11) QNN_F(12) QNN_F(13) QNN_F(14) QNN_F(15)
#undef QNN_F
}

__global__ __launch_bounds__(256, 2)
void qnn_kernel(const float* __restrict__ x, const float* __restrict__ w,
                float* __restrict__ out)
{
    __shared__ float4 rotL[NL * NQ][2];   // (R00,R01) | (R10,R11)

    const int t    = threadIdx.x;
    const int lane = t & 63;
    const int wv   = blockIdx.x * 4 + (t >> 6);   // wave -> elements 2wv, 2wv+1

    if (t < NL * NQ) {
        const float* wp = w + t * 3;
        float phi = wp[0], th = wp[1], om = wp[2];
        float ct = cosf(th * 0.5f), st = sinf(th * 0.5f);
        float ap = (phi + om) * 0.5f, am = (phi - om) * 0.5f;
        float cap = cosf(ap), sap = sinf(ap);
        float cam = cosf(am), sam = sinf(am);
        rotL[t][0] = make_float4(cap * ct, -sap * ct, -cam * st, -sam * st);
        rotL[t][1] = make_float4(cam * st, -sam * st,  cap * ct,  sap * ct);
    }
    __syncthreads();

    // ---- per-batch RY cos/sin pairs; uniformized into SGPRs (R1 pattern) ----
    const float* xb = x + (size_t)__builtin_amdgcn_readfirstlane(wv * 2 * NQ);
    v2f C_[NQ], S_[NQ];
    #pragma unroll
    for (int q = 0; q < NQ; ++q) {
        float x0 = xb[q] * 0.5f, x1 = xb[NQ + q] * 0.5f;
        C_[q] = (v2f){ uf(__cosf(x0)), uf(__cosf(x1)) };
        S_[q] = (v2f){ uf(__sinf(x0)), uf(__sinf(x1)) };
    }

    // ---- layer 1 analytic: product state, both elements at once ----
    v2f re[16], im[16];
    {
        cpx c0[4], c1[4], Ln;
        #pragma unroll
        for (int q = 0; q < NQ; ++q) {
            float4 r0 = rotL[q][0], r1v = rotL[q][1];
            cpx g0, g1;
            g0.re = fmav(sp(r0.x),  C_[q], sp(r0.z)  * S_[q]);
            g0.im = fmav(sp(r0.y),  C_[q], sp(r0.w)  * S_[q]);
            g1.re = fmav(sp(r1v.x), C_[q], sp(r1v.z) * S_[q]);
            g1.im = fmav(sp(r1v.y), C_[q], sp(r1v.w) * S_[q]);
            if (q < 4) { c0[q] = g0; c1[q] = g1; }
            else {
                const bool bit = (lane >> (q - 4)) & 1;
                cpx gg; gg.re = bit ? g1.re : g0.re; gg.im = bit ? g1.im : g0.im;
                Ln = (q == 4) ? gg : cm(Ln, gg);
            }
        }
        cpx S01[4], SH[4];
        #pragma unroll
        for (int j = 0; j < 4; ++j)
            S01[j] = cm((j & 1) ? c1[0] : c0[0], (j & 2) ? c1[1] : c0[1]);
        #pragma unroll
        for (int h = 0; h < 4; ++h)
            SH[h] = cm(cm((h & 1) ? c1[2] : c0[2], (h & 2) ? c1[3] : c0[3]), Ln);
        #pragma unroll
        for (int j = 0; j < 16; ++j) {
            cpx A = cm(S01[j & 3], SH[j >> 2]);
            re[j] = A.re; im[j] = A.im;
        }
    }

    // ---- layers 2..3 (masks + parities verified in R2/R3/R5/R8) ----
#define GATE(IDX, Q, MASK, RMASK)                                             \
    apply_gate<MASK, RMASK>(re, im, rotL[IDX][0], rotL[IDX][1],               \
                            C_[Q], S_[Q], lane);
    GATE(10, 0, 0x003, 0x3FE)  GATE(11, 1, 0x006, 0x003)
    GATE(12, 2, 0x00C, 0x007)  GATE(13, 3, 0x018, 0x00F)
    GATE(14, 4, 0x030, 0x01F)  GATE(15, 5, 0x060, 0x03F)
    GATE(16, 6, 0x0C0, 0x07F)  GATE(17, 7, 0x180, 0x0FF)
    GATE(18, 8, 0x300, 0x1FF)  GATE(19, 9, 0x203, 0x3FF)
    GATE(20, 0, 0x005, 0x2AB)  GATE(21, 1, 0x00A, 0x3FD)
    GATE(22, 2, 0x014, 0x3FA)  GATE(23, 3, 0x028, 0x3F5)
    GATE(24, 4, 0x050, 0x3EA)  GATE(25, 5, 0x0A0, 0x3D5)
    GATE(26, 6, 0x140, 0x3AA)  GATE(27, 7, 0x280, 0x355)
    GATE(28, 8, 0x103, 0x2AA)  GATE(29, 9, 0x206, 0x155)
#undef GATE

    // ---- probabilities + 4-bit Walsh-Hadamard (both elements packed) ----
    v2f P[16];
    #pragma unroll
    for (int j = 0; j < 16; ++j)
        P[j] = fmav(re[j], re[j], im[j] * im[j]);
    #pragma unroll
    for (int bit = 0; bit < 4; ++bit) {
        #pragma unroll
        for (int j = 0; j < 16; ++j)
            if (!(j & (1 << bit))) {
                int k = j | (1 << bit);
                v2f u = P[j], v = P[k];
                P[j] = u + v;
                P[k] = u - v;
            }
    }

    const int bp32 = ((lane ^ 32) << 2);
    v2f vout = {0.f, 0.f};
#define MEAS(Q, RM)                                                           \
    { constexpr int RH_ = ((RM) >> 4) & 63;                                   \
      constexpr int RL_ = (RM) & 15;                                          \
      v2f v = P[RL_];                                                         \
      if (__popc(lane & RH_) & 1) v = -v;                                     \
      v2f tt;                                                                 \
      tt.x = i2f(dppm<177>(f2i(v.x))); tt.y = i2f(dppm<177>(f2i(v.y)));       \
      v += tt;                                   /* xor1  */                  \
      tt.x = i2f(dppm<78>(f2i(v.x)));  tt.y = i2f(dppm<78>(f2i(v.y)));        \
      v += tt;                                   /* xor2  */                  \
      tt.x = i2f(dppm<321>(dppm<27>(f2i(v.x))));                              \
      tt.y = i2f(dppm<321>(dppm<27>(f2i(v.y))));                              \
      v += tt;                                   /* xor4 = 7^3 */             \
      tt.x = i2f(dppm<320>(dppm<321>(f2i(v.x))));                             \
      tt.y = i2f(dppm<320>(dppm<321>(f2i(v.y))));                             \
      v += tt;                                   /* xor8 = 15^7 */            \
      tt.x = i2f(__builtin_amdgcn_ds_swizzle(f2i(v.x), (16 << 10) | 0x1F));   \
      tt.y = i2f(__builtin_amdgcn_ds_swizzle(f2i(v.y), (16 << 10) | 0x1F));   \
      v += tt;                                   /* xor16 */                  \
      tt.x = i2f(__builtin_amdgcn_ds_bpermute(bp32, f2i(v.x)));               \
      tt.y = i2f(__builtin_amdgcn_ds_bpermute(bp32, f2i(v.y)));               \
      v += tt;                                   /* xor32 */                  \
      if (lane == (Q)) vout = v; }
    MEAS(0, 0x0CD) MEAS(1, 0x156) MEAS(2, 0x2AC) MEAS(3, 0x159)
    MEAS(4, 0x2B3) MEAS(5, 0x166) MEAS(6, 0x2CC) MEAS(7, 0x199)
    MEAS(8, 0x333) MEAS(9, 0x266)
#undef MEAS

    if (lane < NQ) {
        out[(wv * 2)     * NQ + lane] = vout.x;
        out[(wv * 2 + 1) * NQ + lane] = vout.y;
    }
}

extern "C" void kernel_launch(void* const* d_in, const int* in_sizes, int n_in,
                              void* d_out, int out_size, void* d_ws, size_t ws_size,
                              hipStream_t stream) {
    const float* x = (const float*)d_in[0];   // (4096, 10) f32
    const float* w = (const float*)d_in[1];   // (3, 10, 3) f32
    float* out = (float*)d_out;               // (4096, 10) f32
    const int B = in_sizes[0] / NQ;           // 4096
    qnn_kernel<<<B / 8, 256, 0, stream>>>(x, w, out);
}